// Round 4
// baseline (385.260 us; speedup 1.0000x reference)
//
#include <hip/hip_runtime.h>
#include <hip/hip_bf16.h>

// CoPE, bf16 I/O (detected on device; f32 path kept). Two-kernel plan:
// k1 (cope_li): li[rows][64] f32 = q @ pos_emb into d_ws.
// k2 (cope_main): 1 wave = 1 row; sigmoid -> diag zero -> wave scan ->
//   suffix pos -> clamp -> lerp gather from per-wave LDS li row (ds_read2).
// Fallback if ws too small: proven round-2 fused kernel, launched TWICE as a
// deliberate +121us timing marker (idempotent) to disambiguate dur_us floor.

__device__ __forceinline__ float bf2f(unsigned short u) {
    union { unsigned int i; float f; } t; t.i = ((unsigned int)u) << 16; return t.f;
}
__device__ __forceinline__ float bf2f_lo(unsigned int v) {
    union { unsigned int i; float f; } t; t.i = v << 16; return t.f;
}
__device__ __forceinline__ float bf2f_hi(unsigned int v) {
    union { unsigned int i; float f; } t; t.i = v & 0xffff0000u; return t.f;
}
__device__ __forceinline__ unsigned short f2bf(float f) {
    union { float f; unsigned int i; } t; t.f = f;
    unsigned int lsb = (t.i >> 16) & 1u;
    t.i += 0x7fffu + lsb;
    return (unsigned short)(t.i >> 16);
}
__device__ __forceinline__ float sigmoid_fast(float x) {
    float e = __builtin_amdgcn_exp2f(-1.44269504f * x);
    return __builtin_amdgcn_rcpf(1.0f + e);
}

__global__ __launch_bounds__(256) void cope_detect(
    const unsigned short* __restrict__ q, int* __restrict__ flag)
{
    const int tid = threadIdx.x;
    unsigned short u = q[2 * tid];          // bf16 values vs f32 low-mantissa words
    int e = (u >> 7) & 0xFF;
    unsigned long long m = __ballot(e >= 200);
    __shared__ int cnt;
    if (tid == 0) cnt = 0;
    __syncthreads();
    if ((tid & 63) == 0) atomicAdd(&cnt, __popcll(m));
    __syncthreads();
    if (tid == 0) *flag = (cnt > 8) ? 1 : 0;   // 1 => float32 buffers
}

// ---------------------------------------------------------------------------
// k1: li[r][n] = sum_d q[r][d] * pe[d][n].  64 rows/block, 256 thr, 4x4 tile.
// ---------------------------------------------------------------------------
__global__ __launch_bounds__(256) void cope_li(
    const void* __restrict__ qv, const void* __restrict__ pev,
    float* __restrict__ li, const int* __restrict__ flag)
{
    __shared__ float pe_f[64 * 64];   // [d][n]
    __shared__ float q_t[64 * 64];    // [d][r_local]
    const int tid = threadIdx.x;
    const bool isf32 = (*flag != 0);

    if (isf32) {
        const float4* pe4 = reinterpret_cast<const float4*>(pev);
#pragma unroll
        for (int it = 0; it < 4; ++it)
            reinterpret_cast<float4*>(pe_f)[it * 256 + tid] = pe4[it * 256 + tid];
        const float4* q4 = reinterpret_cast<const float4*>(qv) + (size_t)blockIdx.x * 1024;
#pragma unroll
        for (int it = 0; it < 4; ++it) {
            int idx = it * 256 + tid;
            int d4 = idx >> 6, rr = idx & 63;
            float4 v = q4[rr * 16 + d4];
            q_t[(d4 * 4 + 0) * 64 + rr] = v.x;
            q_t[(d4 * 4 + 1) * 64 + rr] = v.y;
            q_t[(d4 * 4 + 2) * 64 + rr] = v.z;
            q_t[(d4 * 4 + 3) * 64 + rr] = v.w;
        }
    } else {
        const uint4* pe16 = reinterpret_cast<const uint4*>(pev);
#pragma unroll
        for (int it = 0; it < 2; ++it) {
            int idx = it * 256 + tid;       // 512 uint4 = 4096 bf16
            uint4 v = pe16[idx];
            float4 a, b;
            a.x = bf2f_lo(v.x); a.y = bf2f_hi(v.x);
            a.z = bf2f_lo(v.y); a.w = bf2f_hi(v.y);
            b.x = bf2f_lo(v.z); b.y = bf2f_hi(v.z);
            b.z = bf2f_lo(v.w); b.w = bf2f_hi(v.w);
            float4* dst = reinterpret_cast<float4*>(&pe_f[idx * 8]);
            dst[0] = a; dst[1] = b;
        }
        const ushort4* q4 = reinterpret_cast<const ushort4*>(qv) + (size_t)blockIdx.x * 1024;
#pragma unroll
        for (int it = 0; it < 4; ++it) {
            int idx = it * 256 + tid;
            int d4 = idx >> 6, rr = idx & 63;
            ushort4 v = q4[rr * 16 + d4];
            q_t[(d4 * 4 + 0) * 64 + rr] = bf2f(v.x);
            q_t[(d4 * 4 + 1) * 64 + rr] = bf2f(v.y);
            q_t[(d4 * 4 + 2) * 64 + rr] = bf2f(v.z);
            q_t[(d4 * 4 + 3) * 64 + rr] = bf2f(v.w);
        }
    }
    __syncthreads();

    const int r0 = (tid & 15) * 4, n0 = (tid >> 4) * 4;
    float acc[4][4];
#pragma unroll
    for (int a = 0; a < 4; ++a)
#pragma unroll
        for (int b = 0; b < 4; ++b) acc[a][b] = 0.f;

#pragma unroll 8
    for (int d = 0; d < 64; ++d) {
        float4 qv4 = *reinterpret_cast<const float4*>(&q_t[d * 64 + r0]);
        float4 pv = *reinterpret_cast<const float4*>(&pe_f[d * 64 + n0]);
        acc[0][0] += qv4.x * pv.x; acc[0][1] += qv4.x * pv.y; acc[0][2] += qv4.x * pv.z; acc[0][3] += qv4.x * pv.w;
        acc[1][0] += qv4.y * pv.x; acc[1][1] += qv4.y * pv.y; acc[1][2] += qv4.y * pv.z; acc[1][3] += qv4.y * pv.w;
        acc[2][0] += qv4.z * pv.x; acc[2][1] += qv4.z * pv.y; acc[2][2] += qv4.z * pv.z; acc[2][3] += qv4.z * pv.w;
        acc[3][0] += qv4.w * pv.x; acc[3][1] += qv4.w * pv.y; acc[3][2] += qv4.w * pv.z; acc[3][3] += qv4.w * pv.w;
    }
#pragma unroll
    for (int a = 0; a < 4; ++a) {
        size_t row = (size_t)blockIdx.x * 64 + r0 + a;
        float4 o; o.x = acc[a][0]; o.y = acc[a][1]; o.z = acc[a][2]; o.w = acc[a][3];
        *reinterpret_cast<float4*>(&li[row * 64 + n0]) = o;
    }
}

// ---------------------------------------------------------------------------
// k2: 1 wave = 1 row (4 rows/block). 16 cols/lane. li row in per-wave LDS
// (padded +1) so each lerp gather is one ds_read2_b32. One barrier total.
// ---------------------------------------------------------------------------
__global__ __launch_bounds__(256) void cope_main(
    const void* __restrict__ attnv,
    const float* __restrict__ li_ws,
    void* __restrict__ outv,
    const int* __restrict__ flag)
{
    const int tid = threadIdx.x;
    const int lane = tid & 63;
    const int wid = tid >> 6;
    const int r = blockIdx.x * 4 + wid;     // rows = 49152
    const int i = r & 1023;                 // diagonal column
    const bool isf32 = (*flag != 0);
    const int col0 = lane * 16;

    __shared__ float lrow[4][66];           // 64 + pad; per-wave row

    {
        float lv = li_ws[(size_t)r * 64 + lane];
        lrow[wid][lane] = lv;
        if (lane == 63) lrow[wid][64] = lv; // pad: li[64] = li[63] (w==0 there)
    }

    float g[16];
    if (isf32) {
        const float4* ap = reinterpret_cast<const float4*>(
            reinterpret_cast<const float*>(attnv) + (size_t)r * 1024);
#pragma unroll
        for (int c = 0; c < 4; ++c) {
            float4 v = ap[4 * lane + c];
            int k = c * 4;
            g[k + 0] = (col0 + k + 0 == i) ? 0.f : sigmoid_fast(v.x);
            g[k + 1] = (col0 + k + 1 == i) ? 0.f : sigmoid_fast(v.y);
            g[k + 2] = (col0 + k + 2 == i) ? 0.f : sigmoid_fast(v.z);
            g[k + 3] = (col0 + k + 3 == i) ? 0.f : sigmoid_fast(v.w);
        }
    } else {
        const uint4* ap = reinterpret_cast<const uint4*>(
            reinterpret_cast<const unsigned short*>(attnv) + (size_t)r * 1024);
#pragma unroll
        for (int c = 0; c < 2; ++c) {
            uint4 v = ap[2 * lane + c];
            int k = c * 8;
            g[k + 0] = (col0 + k + 0 == i) ? 0.f : sigmoid_fast(bf2f_lo(v.x));
            g[k + 1] = (col0 + k + 1 == i) ? 0.f : sigmoid_fast(bf2f_hi(v.x));
            g[k + 2] = (col0 + k + 2 == i) ? 0.f : sigmoid_fast(bf2f_lo(v.y));
            g[k + 3] = (col0 + k + 3 == i) ? 0.f : sigmoid_fast(bf2f_hi(v.y));
            g[k + 4] = (col0 + k + 4 == i) ? 0.f : sigmoid_fast(bf2f_lo(v.z));
            g[k + 5] = (col0 + k + 5 == i) ? 0.f : sigmoid_fast(bf2f_hi(v.z));
            g[k + 6] = (col0 + k + 6 == i) ? 0.f : sigmoid_fast(bf2f_lo(v.w));
            g[k + 7] = (col0 + k + 7 == i) ? 0.f : sigmoid_fast(bf2f_hi(v.w));
        }
    }

    float ts = 0.f;
#pragma unroll
    for (int k = 0; k < 16; ++k) ts += g[k];

    // wave-inclusive scan of lane sums
    float x = ts;
#pragma unroll
    for (int s = 1; s < 64; s <<= 1) {
        float y = __shfl_up(x, s, 64);
        if (lane >= s) x += y;
    }
    const float total = __shfl(x, 63, 64);
    float run = x - ts;                     // exclusive prefix before col0

    __syncthreads();                        // lrow visible (also cross-wave safe)

    const float* lr = lrow[wid];
    if (isf32) {
        float* op = reinterpret_cast<float*>(outv) + (size_t)r * 1024;
#pragma unroll
        for (int c = 0; c < 4; ++c) {
            float4 v;
            float o0, o1, o2, o3;
#pragma unroll
            for (int k = 0; k < 4; ++k) {
                int e = c * 4 + k;
                float p = total - run;
                run += g[e];
                p = fminf(fmaxf(p, 0.f), 63.f);
                float pf = floorf(p);
                int ipf = (int)pf;
                float a = lr[ipf], b = lr[ipf + 1];   // ds_read2_b32
                float o = fmaf(p - pf, b - a, a);
                if (k == 0) o0 = o; else if (k == 1) o1 = o; else if (k == 2) o2 = o; else o3 = o;
            }
            v.x = o0; v.y = o1; v.z = o2; v.w = o3;
            reinterpret_cast<float4*>(op)[4 * lane + c] = v;
        }
    } else {
        unsigned short* op = reinterpret_cast<unsigned short*>(outv) + (size_t)r * 1024;
#pragma unroll
        for (int c = 0; c < 2; ++c) {
            unsigned int w01 = 0, w23 = 0, w45 = 0, w67 = 0;
#pragma unroll
            for (int k = 0; k < 8; ++k) {
                int e = c * 8 + k;
                float p = total - run;
                run += g[e];
                p = fminf(fmaxf(p, 0.f), 63.f);
                float pf = floorf(p);
                int ipf = (int)pf;
                float a = lr[ipf], b = lr[ipf + 1];   // ds_read2_b32
                float o = fmaf(p - pf, b - a, a);
                unsigned int ub = f2bf(o);
                if (k == 0) w01 = ub;        else if (k == 1) w01 |= ub << 16;
                else if (k == 2) w23 = ub;   else if (k == 3) w23 |= ub << 16;
                else if (k == 4) w45 = ub;   else if (k == 5) w45 |= ub << 16;
                else if (k == 6) w67 = ub;   else              w67 |= ub << 16;
            }
            uint4 v; v.x = w01; v.y = w23; v.z = w45; v.w = w67;
            reinterpret_cast<uint4*>(op)[2 * lane + c] = v;
        }
    }
}

// ---------------------------------------------------------------------------
// Fallback (ws too small): round-2 fused kernel, known-passing.
// ---------------------------------------------------------------------------
__global__ __launch_bounds__(256) void cope_fused(
    const void* __restrict__ qv, const void* __restrict__ attnv,
    const void* __restrict__ pev, void* __restrict__ outv,
    const int* __restrict__ flag)
{
    const int r = blockIdx.x;
    const int i = r & 1023;
    const int tid = threadIdx.x;
    const int lane = tid & 63;
    const int wid = tid >> 6;
    const bool isf32 = (*flag != 0);

    __shared__ float pe_f[64 * 64];
    __shared__ float q_s[64];
    __shared__ float li[64];
    __shared__ float wsum[4];

    float g[4];
    if (isf32) {
        const float4* pe4 = reinterpret_cast<const float4*>(pev);
#pragma unroll
        for (int it = 0; it < 4; ++it)
            reinterpret_cast<float4*>(pe_f)[it * 256 + tid] = pe4[it * 256 + tid];
        if (tid < 16) {
            float4 v = reinterpret_cast<const float4*>(qv)[(size_t)r * 16 + tid];
            q_s[tid * 4 + 0] = v.x; q_s[tid * 4 + 1] = v.y;
            q_s[tid * 4 + 2] = v.z; q_s[tid * 4 + 3] = v.w;
        }
        float4 av = reinterpret_cast<const float4*>(attnv)[(size_t)r * 256 + tid];
        g[0] = sigmoid_fast(av.x); g[1] = sigmoid_fast(av.y);
        g[2] = sigmoid_fast(av.z); g[3] = sigmoid_fast(av.w);
    } else {
        const uint4* pe16 = reinterpret_cast<const uint4*>(pev);
#pragma unroll
        for (int it = 0; it < 2; ++it) {
            int idx = it * 256 + tid;
            uint4 v = pe16[idx];
            float4 a, b;
            a.x = bf2f_lo(v.x); a.y = bf2f_hi(v.x);
            a.z = bf2f_lo(v.y); a.w = bf2f_hi(v.y);
            b.x = bf2f_lo(v.z); b.y = bf2f_hi(v.z);
            b.z = bf2f_lo(v.w); b.w = bf2f_hi(v.w);
            float4* dst = reinterpret_cast<float4*>(&pe_f[idx * 8]);
            dst[0] = a; dst[1] = b;
        }
        if (tid < 16) {
            ushort4 v = reinterpret_cast<const ushort4*>(qv)[(size_t)r * 16 + tid];
            q_s[tid * 4 + 0] = bf2f(v.x); q_s[tid * 4 + 1] = bf2f(v.y);
            q_s[tid * 4 + 2] = bf2f(v.z); q_s[tid * 4 + 3] = bf2f(v.w);
        }
        ushort4 av = reinterpret_cast<const ushort4*>(attnv)[(size_t)r * 256 + tid];
        g[0] = sigmoid_fast(bf2f(av.x)); g[1] = sigmoid_fast(bf2f(av.y));
        g[2] = sigmoid_fast(bf2f(av.z)); g[3] = sigmoid_fast(bf2f(av.w));
    }

    const int j0 = tid * 4;
    if (i >= j0 && i < j0 + 4) g[i - j0] = 0.f;
    float ts = g[0] + g[1] + g[2] + g[3];
    float x = ts;
#pragma unroll
    for (int s = 1; s < 64; s <<= 1) {
        float y = __shfl_up(x, s, 64);
        if (lane >= s) x += y;
    }
    if (lane == 63) wsum[wid] = x;
    __syncthreads();
    if (tid < 64) {
        float acc = 0.f;
#pragma unroll
        for (int d = 0; d < 64; ++d) acc += q_s[d] * pe_f[d * 64 + tid];
        li[tid] = acc;
    }
    const float s0 = wsum[0], s1 = wsum[1], s2 = wsum[2], s3 = wsum[3];
    const float total = s0 + s1 + s2 + s3;
    float woff = 0.f;
    if (wid > 0) woff += s0;
    if (wid > 1) woff += s1;
    if (wid > 2) woff += s2;
    float run = woff + (x - ts);
    __syncthreads();

    float o[4];
#pragma unroll
    for (int e = 0; e < 4; ++e) {
        float p = total - run;
        run += g[e];
        p = fminf(fmaxf(p, 0.f), 63.f);
        float pf = floorf(p);
        int ipf = (int)pf;
        int ipc = min(ipf + 1, 63);
        float w = p - pf;
        o[e] = li[ipf] + w * (li[ipc] - li[ipf]);
    }
    if (isf32) {
        float4 ov; ov.x = o[0]; ov.y = o[1]; ov.z = o[2]; ov.w = o[3];
        reinterpret_cast<float4*>(outv)[(size_t)r * 256 + tid] = ov;
    } else {
        ushort4 ov;
        ov.x = f2bf(o[0]); ov.y = f2bf(o[1]); ov.z = f2bf(o[2]); ov.w = f2bf(o[3]);
        reinterpret_cast<ushort4*>(outv)[(size_t)r * 256 + tid] = ov;
    }
}

extern "C" void kernel_launch(void* const* d_in, const int* in_sizes, int n_in,
                              void* d_out, int out_size, void* d_ws, size_t ws_size,
                              hipStream_t stream) {
    const void* q    = d_in[0];
    const void* attn = d_in[1];
    const void* pe   = d_in[2];
    int* flag = (int*)d_ws;
    float* li = (float*)((char*)d_ws + 256);

    const long L = 1024;
    const long rows = (long)in_sizes[1] / L;   // 49152
    const size_t ws_need = 256 + (size_t)rows * 64 * sizeof(float);

    cope_detect<<<1, 256, 0, stream>>>((const unsigned short*)d_in[0], flag);
    if (ws_size >= ws_need) {
        cope_li<<<(int)(rows / 64), 256, 0, stream>>>(q, pe, li, flag);
        cope_main<<<(int)(rows / 4), 256, 0, stream>>>(attn, li, d_out, flag);
    } else {
        // Diagnostic marker: fallback runs fused TWICE (idempotent, same output)
        // so a ws-fallback execution is unambiguous in dur_us (+~121us).
        cope_fused<<<(int)rows, 256, 0, stream>>>(q, attn, pe, d_out, flag);
        cope_fused<<<(int)rows, 256, 0, stream>>>(q, attn, pe, d_out, flag);
    }
}

// Round 5
// 341.162 us; speedup vs baseline: 1.1293x; 1.1293x over previous
//
#include <hip/hip_runtime.h>
#include <hip/hip_bf16.h>

// CoPE, bf16 I/O (device-detected; f32 path kept). dur_us carries ~234us of
// harness fill/restore floor; our budget is the kernels themselves.
// k1 (cope_li): li[rows][64] f32 = q @ pos_emb into d_ws (amortizes pos_emb
//   staging over 64 rows).
// k2 (cope_row): round-2-proven thin-thread shape: 1 block = 1 row, 256 thr,
//   4 cols/thread (max TLP for latency hiding), li row from ws in tiny LDS,
//   ONE barrier, scalar ds_read gathers over 65-word padded row.

__device__ __forceinline__ float bf2f(unsigned short u) {
    union { unsigned int i; float f; } t; t.i = ((unsigned int)u) << 16; return t.f;
}
__device__ __forceinline__ float bf2f_lo(unsigned int v) {
    union { unsigned int i; float f; } t; t.i = v << 16; return t.f;
}
__device__ __forceinline__ float bf2f_hi(unsigned int v) {
    union { unsigned int i; float f; } t; t.i = v & 0xffff0000u; return t.f;
}
__device__ __forceinline__ unsigned short f2bf(float f) {
    union { float f; unsigned int i; } t; t.f = f;
    unsigned int lsb = (t.i >> 16) & 1u;
    t.i += 0x7fffu + lsb;
    return (unsigned short)(t.i >> 16);
}
__device__ __forceinline__ float sigmoid_fast(float x) {
    float e = __builtin_amdgcn_exp2f(-1.44269504f * x);
    return __builtin_amdgcn_rcpf(1.0f + e);
}

__global__ __launch_bounds__(256) void cope_detect(
    const unsigned short* __restrict__ q, int* __restrict__ flag)
{
    const int tid = threadIdx.x;
    unsigned short u = q[2 * tid];
    int e = (u >> 7) & 0xFF;
    unsigned long long m = __ballot(e >= 200);
    __shared__ int cnt;
    if (tid == 0) cnt = 0;
    __syncthreads();
    if ((tid & 63) == 0) atomicAdd(&cnt, __popcll(m));
    __syncthreads();
    if (tid == 0) *flag = (cnt > 8) ? 1 : 0;   // 1 => float32 buffers
}

// ---------------------------------------------------------------------------
// k1: li[r][n] = sum_d q[r][d] * pe[d][n].  64 rows/block, 256 thr, 4x4 tile.
// ---------------------------------------------------------------------------
__global__ __launch_bounds__(256) void cope_li(
    const void* __restrict__ qv, const void* __restrict__ pev,
    float* __restrict__ li, const int* __restrict__ flag)
{
    __shared__ float pe_f[64 * 64];   // [d][n]
    __shared__ float q_t[64 * 64];    // [d][r_local]
    const int tid = threadIdx.x;
    const bool isf32 = (*flag != 0);

    if (isf32) {
        const float4* pe4 = reinterpret_cast<const float4*>(pev);
#pragma unroll
        for (int it = 0; it < 4; ++it)
            reinterpret_cast<float4*>(pe_f)[it * 256 + tid] = pe4[it * 256 + tid];
        const float4* q4 = reinterpret_cast<const float4*>(qv) + (size_t)blockIdx.x * 1024;
#pragma unroll
        for (int it = 0; it < 4; ++it) {
            int idx = it * 256 + tid;
            int d4 = idx >> 6, rr = idx & 63;
            float4 v = q4[rr * 16 + d4];
            q_t[(d4 * 4 + 0) * 64 + rr] = v.x;
            q_t[(d4 * 4 + 1) * 64 + rr] = v.y;
            q_t[(d4 * 4 + 2) * 64 + rr] = v.z;
            q_t[(d4 * 4 + 3) * 64 + rr] = v.w;
        }
    } else {
        const uint4* pe16 = reinterpret_cast<const uint4*>(pev);
#pragma unroll
        for (int it = 0; it < 2; ++it) {
            int idx = it * 256 + tid;       // 512 uint4 = 4096 bf16
            uint4 v = pe16[idx];
            float4 a, b;
            a.x = bf2f_lo(v.x); a.y = bf2f_hi(v.x);
            a.z = bf2f_lo(v.y); a.w = bf2f_hi(v.y);
            b.x = bf2f_lo(v.z); b.y = bf2f_hi(v.z);
            b.z = bf2f_lo(v.w); b.w = bf2f_hi(v.w);
            float4* dst = reinterpret_cast<float4*>(&pe_f[idx * 8]);
            dst[0] = a; dst[1] = b;
        }
        const ushort4* q4 = reinterpret_cast<const ushort4*>(qv) + (size_t)blockIdx.x * 1024;
#pragma unroll
        for (int it = 0; it < 4; ++it) {
            int idx = it * 256 + tid;
            int d4 = idx >> 6, rr = idx & 63;
            ushort4 v = q4[rr * 16 + d4];
            q_t[(d4 * 4 + 0) * 64 + rr] = bf2f(v.x);
            q_t[(d4 * 4 + 1) * 64 + rr] = bf2f(v.y);
            q_t[(d4 * 4 + 2) * 64 + rr] = bf2f(v.z);
            q_t[(d4 * 4 + 3) * 64 + rr] = bf2f(v.w);
        }
    }
    __syncthreads();

    const int r0 = (tid & 15) * 4, n0 = (tid >> 4) * 4;
    float acc[4][4];
#pragma unroll
    for (int a = 0; a < 4; ++a)
#pragma unroll
        for (int b = 0; b < 4; ++b) acc[a][b] = 0.f;

#pragma unroll 8
    for (int d = 0; d < 64; ++d) {
        float4 qv4 = *reinterpret_cast<const float4*>(&q_t[d * 64 + r0]);
        float4 pv = *reinterpret_cast<const float4*>(&pe_f[d * 64 + n0]);
        acc[0][0] += qv4.x * pv.x; acc[0][1] += qv4.x * pv.y; acc[0][2] += qv4.x * pv.z; acc[0][3] += qv4.x * pv.w;
        acc[1][0] += qv4.y * pv.x; acc[1][1] += qv4.y * pv.y; acc[1][2] += qv4.y * pv.z; acc[1][3] += qv4.y * pv.w;
        acc[2][0] += qv4.z * pv.x; acc[2][1] += qv4.z * pv.y; acc[2][2] += qv4.z * pv.z; acc[2][3] += qv4.z * pv.w;
        acc[3][0] += qv4.w * pv.x; acc[3][1] += qv4.w * pv.y; acc[3][2] += qv4.w * pv.z; acc[3][3] += qv4.w * pv.w;
    }
#pragma unroll
    for (int a = 0; a < 4; ++a) {
        size_t row = (size_t)blockIdx.x * 64 + r0 + a;
        float4 o; o.x = acc[a][0]; o.y = acc[a][1]; o.z = acc[a][2]; o.w = acc[a][3];
        *reinterpret_cast<float4*>(&li[row * 64 + n0]) = o;
    }
}

// ---------------------------------------------------------------------------
// k2: 1 block = 1 row, 256 threads x 4 columns. One barrier. Tiny LDS.
// ---------------------------------------------------------------------------
__global__ __launch_bounds__(256) void cope_row(
    const void* __restrict__ attnv,
    const float* __restrict__ li_ws,
    void* __restrict__ outv,
    const int* __restrict__ flag)
{
    const int r = blockIdx.x;               // 49152 rows
    const int i = r & 1023;                 // diagonal column
    const int tid = threadIdx.x;
    const int lane = tid & 63;
    const int wid = tid >> 6;
    const bool isf32 = (*flag != 0);

    __shared__ float li[65];                // 64 + pad (li[64]=li[63], w==0 there)
    __shared__ float wsum[4];

    if (tid < 64) {
        float lv = li_ws[(size_t)r * 64 + tid];
        li[tid] = lv;
        if (tid == 63) li[64] = lv;
    }

    float g[4];
    if (isf32) {
        float4 av = reinterpret_cast<const float4*>(attnv)[(size_t)r * 256 + tid];
        g[0] = sigmoid_fast(av.x); g[1] = sigmoid_fast(av.y);
        g[2] = sigmoid_fast(av.z); g[3] = sigmoid_fast(av.w);
    } else {
        ushort4 av = reinterpret_cast<const ushort4*>(attnv)[(size_t)r * 256 + tid];
        g[0] = sigmoid_fast(bf2f(av.x)); g[1] = sigmoid_fast(bf2f(av.y));
        g[2] = sigmoid_fast(bf2f(av.z)); g[3] = sigmoid_fast(bf2f(av.w));
    }

    const int j0 = tid * 4;
    if (i >= j0 && i < j0 + 4) g[i - j0] = 0.f;   // zero diagonal

    float ts = g[0] + g[1] + g[2] + g[3];

    // wave-inclusive scan of per-thread sums
    float x = ts;
#pragma unroll
    for (int s = 1; s < 64; s <<= 1) {
        float y = __shfl_up(x, s, 64);
        if (lane >= s) x += y;
    }
    if (lane == 63) wsum[wid] = x;

    __syncthreads();                        // li + wsum visible

    const float s0 = wsum[0], s1 = wsum[1], s2 = wsum[2], s3 = wsum[3];
    const float total = s0 + s1 + s2 + s3;
    float woff = 0.f;
    if (wid > 0) woff += s0;
    if (wid > 1) woff += s1;
    if (wid > 2) woff += s2;
    float run = woff + (x - ts);            // exclusive prefix before col j0

    float o[4];
#pragma unroll
    for (int e = 0; e < 4; ++e) {
        float p = total - run;              // inclusive suffix sum at j0+e
        run += g[e];
        p = fminf(fmaxf(p, 0.f), 63.f);
        float pf = floorf(p);
        int ipf = (int)pf;
        float a = li[ipf], b = li[ipf + 1];
        o[e] = fmaf(p - pf, b - a, a);
    }

    if (isf32) {
        float4 ov; ov.x = o[0]; ov.y = o[1]; ov.z = o[2]; ov.w = o[3];
        reinterpret_cast<float4*>(outv)[(size_t)r * 256 + tid] = ov;
    } else {
        uint2 ov;
        ov.x = (unsigned)f2bf(o[0]) | ((unsigned)f2bf(o[1]) << 16);
        ov.y = (unsigned)f2bf(o[2]) | ((unsigned)f2bf(o[3]) << 16);
        reinterpret_cast<uint2*>(outv)[(size_t)r * 256 + tid] = ov;
    }
}

// ---------------------------------------------------------------------------
// Fallback (ws too small): round-2 fused kernel, known-passing.
// ---------------------------------------------------------------------------
__global__ __launch_bounds__(256) void cope_fused(
    const void* __restrict__ qv, const void* __restrict__ attnv,
    const void* __restrict__ pev, void* __restrict__ outv,
    const int* __restrict__ flag)
{
    const int r = blockIdx.x;
    const int i = r & 1023;
    const int tid = threadIdx.x;
    const int lane = tid & 63;
    const int wid = tid >> 6;
    const bool isf32 = (*flag != 0);

    __shared__ float pe_f[64 * 64];
    __shared__ float q_s[64];
    __shared__ float li[64];
    __shared__ float wsum[4];

    float g[4];
    if (isf32) {
        const float4* pe4 = reinterpret_cast<const float4*>(pev);
#pragma unroll
        for (int it = 0; it < 4; ++it)
            reinterpret_cast<float4*>(pe_f)[it * 256 + tid] = pe4[it * 256 + tid];
        if (tid < 16) {
            float4 v = reinterpret_cast<const float4*>(qv)[(size_t)r * 16 + tid];
            q_s[tid * 4 + 0] = v.x; q_s[tid * 4 + 1] = v.y;
            q_s[tid * 4 + 2] = v.z; q_s[tid * 4 + 3] = v.w;
        }
        float4 av = reinterpret_cast<const float4*>(attnv)[(size_t)r * 256 + tid];
        g[0] = sigmoid_fast(av.x); g[1] = sigmoid_fast(av.y);
        g[2] = sigmoid_fast(av.z); g[3] = sigmoid_fast(av.w);
    } else {
        const uint4* pe16 = reinterpret_cast<const uint4*>(pev);
#pragma unroll
        for (int it = 0; it < 2; ++it) {
            int idx = it * 256 + tid;
            uint4 v = pe16[idx];
            float4 a, b;
            a.x = bf2f_lo(v.x); a.y = bf2f_hi(v.x);
            a.z = bf2f_lo(v.y); a.w = bf2f_hi(v.y);
            b.x = bf2f_lo(v.z); b.y = bf2f_hi(v.z);
            b.z = bf2f_lo(v.w); b.w = bf2f_hi(v.w);
            float4* dst = reinterpret_cast<float4*>(&pe_f[idx * 8]);
            dst[0] = a; dst[1] = b;
        }
        if (tid < 16) {
            ushort4 v = reinterpret_cast<const ushort4*>(qv)[(size_t)r * 16 + tid];
            q_s[tid * 4 + 0] = bf2f(v.x); q_s[tid * 4 + 1] = bf2f(v.y);
            q_s[tid * 4 + 2] = bf2f(v.z); q_s[tid * 4 + 3] = bf2f(v.w);
        }
        ushort4 av = reinterpret_cast<const ushort4*>(attnv)[(size_t)r * 256 + tid];
        g[0] = sigmoid_fast(bf2f(av.x)); g[1] = sigmoid_fast(bf2f(av.y));
        g[2] = sigmoid_fast(bf2f(av.z)); g[3] = sigmoid_fast(bf2f(av.w));
    }

    const int j0 = tid * 4;
    if (i >= j0 && i < j0 + 4) g[i - j0] = 0.f;
    float ts = g[0] + g[1] + g[2] + g[3];
    float x = ts;
#pragma unroll
    for (int s = 1; s < 64; s <<= 1) {
        float y = __shfl_up(x, s, 64);
        if (lane >= s) x += y;
    }
    if (lane == 63) wsum[wid] = x;
    __syncthreads();
    if (tid < 64) {
        float acc = 0.f;
#pragma unroll
        for (int d = 0; d < 64; ++d) acc += q_s[d] * pe_f[d * 64 + tid];
        li[tid] = acc;
    }
    const float s0 = wsum[0], s1 = wsum[1], s2 = wsum[2], s3 = wsum[3];
    const float total = s0 + s1 + s2 + s3;
    float woff = 0.f;
    if (wid > 0) woff += s0;
    if (wid > 1) woff += s1;
    if (wid > 2) woff += s2;
    float run = woff + (x - ts);
    __syncthreads();

    float o[4];
#pragma unroll
    for (int e = 0; e < 4; ++e) {
        float p = total - run;
        run += g[e];
        p = fminf(fmaxf(p, 0.f), 63.f);
        float pf = floorf(p);
        int ipf = (int)pf;
        int ipc = min(ipf + 1, 63);
        float w = p - pf;
        o[e] = li[ipf] + w * (li[ipc] - li[ipf]);
    }
    if (isf32) {
        float4 ov; ov.x = o[0]; ov.y = o[1]; ov.z = o[2]; ov.w = o[3];
        reinterpret_cast<float4*>(outv)[(size_t)r * 256 + tid] = ov;
    } else {
        ushort4 ov;
        ov.x = f2bf(o[0]); ov.y = f2bf(o[1]); ov.z = f2bf(o[2]); ov.w = f2bf(o[3]);
        reinterpret_cast<ushort4*>(outv)[(size_t)r * 256 + tid] = ov;
    }
}

extern "C" void kernel_launch(void* const* d_in, const int* in_sizes, int n_in,
                              void* d_out, int out_size, void* d_ws, size_t ws_size,
                              hipStream_t stream) {
    const void* q    = d_in[0];
    const void* attn = d_in[1];
    const void* pe   = d_in[2];
    int* flag = (int*)d_ws;
    float* li = (float*)((char*)d_ws + 256);

    const long L = 1024;
    const long rows = (long)in_sizes[1] / L;   // 49152
    const size_t ws_need = 256 + (size_t)rows * 64 * sizeof(float);

    cope_detect<<<1, 256, 0, stream>>>((const unsigned short*)d_in[0], flag);
    if (ws_size >= ws_need) {
        cope_li<<<(int)(rows / 64), 256, 0, stream>>>(q, pe, li, flag);
        cope_row<<<(int)rows, 256, 0, stream>>>(attn, li, d_out, flag);
    } else {
        cope_fused<<<(int)rows, 256, 0, stream>>>(q, attn, pe, d_out, flag);
    }
}